// Round 3
// baseline (83.278 us; speedup 1.0000x reference)
//
#include <hip/hip_runtime.h>
#include <stdint.h>

#define T_ROWS 256
#define KF 4096
#define OF 11008
#define WROW 2240   // packed W row: 1856 B (4-bit, +8 nibbles) + 256 B (6-bit i8) + 128 B (8-bit i8)
// grouped (dest) segment layout: [0,3712) 4-bit, [3712,3968) 6-bit, [3968,4096) 8-bit

typedef int   v4i __attribute__((ext_vector_type(4)));
typedef float v4f __attribute__((ext_vector_type(4)));
typedef unsigned int u32;

typedef const __attribute__((address_space(1))) uint8_t* gptr_t;
typedef __attribute__((address_space(3))) uint8_t* lptr_t;

// ---------------------------------------------------------------------------
// Kernel 0: stable partition of source columns by segment (wave shfl-scans).
// ---------------------------------------------------------------------------
__global__ __launch_bounds__(256) void perm_k(const int* __restrict__ idx,
                                              int* __restrict__ src_of) {
    __shared__ uint8_t g[KF];
    __shared__ int cnt[3][256];
    __shared__ int exc[3][256];
    const int t = threadIdx.x;
    for (int i = 0; i < 16; ++i) {
        int p = t * 16 + i;
        int seg = p < 3712 ? 0 : (p < 3968 ? 1 : 2);
        g[idx[p]] = (uint8_t)seg;
    }
    __syncthreads();
    int c0 = 0, c1 = 0, c2 = 0;
    for (int i = 0; i < 16; ++i) {
        int s = g[t * 16 + i];
        c0 += (s == 0); c1 += (s == 1); c2 += (s == 2);
    }
    cnt[0][t] = c0; cnt[1][t] = c1; cnt[2][t] = c2;
    __syncthreads();
    if (t < 192) {                       // wave s scans segment s
        int s = t >> 6, l = t & 63;
        int run = 0;
        for (int j = 0; j < 4; ++j) {
            int x = cnt[s][j * 64 + l];
            int inc = x;
#pragma unroll
            for (int off = 1; off < 64; off <<= 1) {
                int y = __shfl_up(inc, off);
                if (l >= off) inc += y;
            }
            exc[s][j * 64 + l] = run + inc - x;
            run += __shfl(inc, 63);
        }
    }
    __syncthreads();
    int off0 = exc[0][t], off1 = 3712 + exc[1][t], off2 = 3968 + exc[2][t];
    for (int i = 0; i < 16; ++i) {
        int c = t * 16 + i;
        int s = g[c];
        int d = (s == 0) ? off0++ : (s == 1) ? off1++ : off2++;
        src_of[d] = c;
    }
}

// ---------------------------------------------------------------------------
// Kernel 1: quantize. b<256: x rows -> qX (signed i8, 4096B rows) + sX + S0X
// (seg0 rowsum). b>=256: W rows -> qWp (packed 2240B rows) + sW.
// global_load_lds staging; gather resolved in LDS; thread t owns dest
// [16t,16t+16) (one segment each: 3712=232*16, 256=16*16, 128=8*16).
// ---------------------------------------------------------------------------
__global__ __launch_bounds__(256) void quant_k(const float* __restrict__ x,
                                               const float* __restrict__ W,
                                               const int* __restrict__ src_of,
                                               int8_t* __restrict__ qX,
                                               uint8_t* __restrict__ qWp,
                                               float* __restrict__ sX,
                                               float* __restrict__ sW,
                                               int* __restrict__ S0X) {
    __shared__ float rowbuf[KF];
    __shared__ float lmax[256];
    __shared__ float sm[3];
    __shared__ int isum[256];
    const int b = blockIdx.x;
    const int t = threadIdx.x;
    const int w = t >> 6, lane = t & 63;
    const bool isX = b < T_ROWS;
    const int r = isX ? b : b - T_ROWS;
    const float* row = (isX ? x : W) + (size_t)r * KF;

    // async stage 16 KB: 4 x 16B per thread, wave-uniform LDS base + lane*16
#pragma unroll
    for (int j = 0; j < 4; ++j) {
        const uint8_t* src = (const uint8_t*)(row + j * 1024 + t * 4);
        __builtin_amdgcn_global_load_lds((gptr_t)src, (lptr_t)&rowbuf[j * 1024 + w * 256], 16, 0, 0);
    }

    const int seg = t < 232 ? 0 : (t < 248 ? 1 : 2);
    const float qmax = seg == 0 ? 7.f : (seg == 1 ? 31.f : 127.f);
    int c[16];
#pragma unroll
    for (int i = 0; i < 4; ++i) {
        v4i ci = *(const v4i*)&src_of[t * 16 + i * 4];
        c[i*4+0] = ci[0]; c[i*4+1] = ci[1]; c[i*4+2] = ci[2]; c[i*4+3] = ci[3];
    }
    __syncthreads();

    float v[16];
    float mx = 0.f;
#pragma unroll
    for (int i = 0; i < 16; ++i) { v[i] = rowbuf[c[i]]; mx = fmaxf(mx, fabsf(v[i])); }
    lmax[t] = mx;
    __syncthreads();
    if (w == 0) {
        float m = fmaxf(fmaxf(lmax[lane], lmax[lane + 64]), lmax[lane + 128]);
        if (lane < 40) m = fmaxf(m, lmax[lane + 192]);
#pragma unroll
        for (int off = 32; off; off >>= 1) m = fmaxf(m, __shfl_xor(m, off));
        if (lane == 0) sm[0] = m;
    } else if (w == 1) {
        float m = lane < 16 ? lmax[232 + lane] : 0.f;
#pragma unroll
        for (int off = 8; off; off >>= 1) m = fmaxf(m, __shfl_xor(m, off));
        if (lane == 0) sm[1] = m;
    } else if (w == 2) {
        float m = lane < 8 ? lmax[248 + lane] : 0.f;
#pragma unroll
        for (int off = 4; off; off >>= 1) m = fmaxf(m, __shfl_xor(m, off));
        if (lane == 0) sm[2] = m;
    }
    __syncthreads();
    float s = sm[seg] / qmax;
    if (s == 0.f) s = 1.f;
    if (t == 0 || t == 232 || t == 248)
        (isX ? sX : sW)[seg * (isX ? T_ROWS : OF) + r] = s;

    int q[16];
#pragma unroll
    for (int i = 0; i < 16; ++i)
        q[i] = (int)rintf(fminf(fmaxf(v[i] / s, -qmax), qmax));  // RNE == np.round

    if (isX) {
        int ss = 0;
        union { int8_t bb[16]; v4i vv; } u;
#pragma unroll
        for (int i = 0; i < 16; ++i) { u.bb[i] = (int8_t)q[i]; ss += q[i]; }
        isum[t] = (seg == 0) ? ss : 0;
        *(v4i*)(qX + (size_t)r * KF + t * 16) = u.vv;
        __syncthreads();
        if (w == 0) {
            int v2 = isum[lane] + isum[lane + 64] + isum[lane + 128] + isum[lane + 192];
#pragma unroll
            for (int off = 32; off; off >>= 1) v2 += __shfl_xor(v2, off);
            if (lane == 0) S0X[r] = v2;
        }
    } else {
        uint8_t* wrow = qWp + (size_t)r * WROW;
        if (seg == 0) {
            u32 pk[2] = {0, 0};
#pragma unroll
            for (int j = 0; j < 8; ++j) {
                u32 byte = (u32)(q[2*j] + 8) | ((u32)(q[2*j+1] + 8) << 4);
                pk[j >> 2] |= byte << ((j & 3) * 8);
            }
            *(u32*)(wrow + t * 8) = pk[0];
            *(u32*)(wrow + t * 8 + 4) = pk[1];
        } else {
            union { int8_t bb[16]; v4i vv; } u;
#pragma unroll
            for (int i = 0; i < 16; ++i) u.bb[i] = (int8_t)q[i];
            const int off = (seg == 1) ? 1856 + (t - 232) * 16 : 2112 + (t - 248) * 16;
            *(v4i*)(wrow + off) = u.vv;
        }
    }
}

// ---------------------------------------------------------------------------
// Kernel 2: int8 MFMA GEMM, 128x64 tile, grid 344, 4 waves. BK=128, 32 steps.
// A: global_load_lds into 3-slot LDS ring (source pre-swizzled, linear dest).
// B: reg-staged from packed qWp (nibble unpack via v_perm), swizzled ds_write,
//    2-buffer. Counted vmcnt keeps 1 step in flight across the per-step
//    barrier. Segment flushes at steps 28/30; seg0 corrected by -8*S0X.
// ---------------------------------------------------------------------------
__global__ __launch_bounds__(256, 2)
void gemm_k(const int8_t* __restrict__ qX, const uint8_t* __restrict__ qWp,
            const float* __restrict__ sX, const float* __restrict__ sW,
            const int* __restrict__ S0X,
            const float* __restrict__ bias, float* __restrict__ out) {
    __shared__ __align__(16) int8_t lA[3][128 * 128];
    __shared__ __align__(16) int8_t lB[2][64 * 128];

    const int bid = blockIdx.x;
    const int swz = (bid & 7) * 43 + (bid >> 3);  // 344 = 8*43: bijective
    const int mb = swz & 1;
    const int nb = swz >> 1;
    const int row0 = mb * 128;
    const int col0 = nb * 64;
    const int tid = threadIdx.x;
    const int lane = tid & 63;
    const int w = tid >> 6;
    const int lr = lane >> 3, lc = lane & 7;
    const int brow = tid >> 2;   // 0..63: B staging row
    const int bch  = tid & 3;    // 0..3:  B staging chunk

    v4i iacc[2][4];
    v4f facc[2][4];
#pragma unroll
    for (int m = 0; m < 2; ++m)
#pragma unroll
        for (int n = 0; n < 4; ++n) {
            iacc[m][n][0]=0; iacc[m][n][1]=0; iacc[m][n][2]=0; iacc[m][n][3]=0;
            facc[m][n][0]=0.f; facc[m][n][1]=0.f; facc[m][n][2]=0.f; facc[m][n][3]=0.f;
        }

    auto stageA = [&](int slot, int step) {
        const int k0 = step * 128;
        const int sc = (lc ^ lr) << 4;            // pre-swizzled source chunk
#pragma unroll
        for (int j = 0; j < 4; ++j) {
            const int row = j * 32 + w * 8;
            const uint8_t* src = (const uint8_t*)qX + (size_t)(row0 + row + lr) * KF + k0 + sc;
            __builtin_amdgcn_global_load_lds((gptr_t)src, (lptr_t)&lA[slot][row * 128], 16, 0, 0);
        }
    };

    auto loadB = [&](v4i (&rs)[2], int step) {
        const uint8_t* rb = qWp + (size_t)(col0 + brow) * WROW;
        if (step <= 28) {                          // packed 4-bit
            rs[0] = *(const v4i*)(rb + step * 64 + bch * 16);
        } else {                                   // i8 segs at offset k0-1856
            const int off = step * 128 - 1856;
            rs[0] = *(const v4i*)(rb + off + bch * 32);
            rs[1] = *(const v4i*)(rb + off + bch * 32 + 16);
        }
    };

    auto writeB = [&](v4i (&rs)[2], int step) {
        int8_t* dst = &lB[step & 1][0];
        const int swr = brow & 7;
        v4i w0, w1;
        if (step <= 28) {
#pragma unroll
            for (int qq = 0; qq < 4; ++qq) {
                u32 wd = ((u32)((const int*)&rs[0])[qq]);
                u32 lo = wd & 0x0F0F0F0Fu;
                u32 hi = (wd >> 4) & 0x0F0F0F0Fu;
                u32 e0 = __builtin_amdgcn_perm(hi, lo, 0x05010400u);  // elems 8q..8q+3
                u32 e1 = __builtin_amdgcn_perm(hi, lo, 0x07030602u);  // elems 8q+4..8q+7
                if (qq < 2) { w0[2*qq] = (int)e0; w0[2*qq+1] = (int)e1; }
                else        { w1[2*(qq-2)] = (int)e0; w1[2*(qq-2)+1] = (int)e1; }
            }
        } else {
            w0 = rs[0]; w1 = rs[1];
        }
        *(v4i*)(dst + brow * 128 + ((2 * bch)     ^ swr) * 16) = w0;
        *(v4i*)(dst + brow * 128 + ((2 * bch + 1) ^ swr) * 16) = w1;
    };

    auto flush = [&](int seg) {
#pragma unroll
        for (int m = 0; m < 2; ++m) {
            float sa[4]; int s0[4];
#pragma unroll
            for (int rr = 0; rr < 4; ++rr) {
                const int rg = row0 + w * 32 + m * 16 + ((lane >> 4) << 2) + rr;
                sa[rr] = sX[seg * T_ROWS + rg];
                s0[rr] = (seg == 0) ? S0X[rg] : 0;
            }
#pragma unroll
            for (int n = 0; n < 4; ++n) {
                const float sb = sW[seg * OF + col0 + n * 16 + (lane & 15)];
#pragma unroll
                for (int rr = 0; rr < 4; ++rr) {
                    const int v = iacc[m][n][rr] - 8 * s0[rr];
                    facc[m][n][rr] += (float)v * (sa[rr] * sb);
                    iacc[m][n][rr] = 0;
                }
            }
        }
    };

    auto body = [&](int t, v4i (&rsLoad)[2], v4i (&rsWrite)[2]) {
        __builtin_amdgcn_s_barrier();
        v4i a[2][2], bfr[4][2];
        const int kg = lane >> 4;
        const int8_t* pa = &lA[t % 3][0];
        const int8_t* pb = &lB[t & 1][0];
#pragma unroll
        for (int m = 0; m < 2; ++m) {
            const int row = w * 32 + m * 16 + (lane & 15);
#pragma unroll
            for (int kk = 0; kk < 2; ++kk) {
                const int ch = (kk * 4 + kg) ^ (row & 7);
                a[m][kk] = *(const v4i*)(pa + row * 128 + ch * 16);
            }
        }
#pragma unroll
        for (int n = 0; n < 4; ++n) {
            const int row = n * 16 + (lane & 15);
#pragma unroll
            for (int kk = 0; kk < 2; ++kk) {
                const int ch = (kk * 4 + kg) ^ (row & 7);
                bfr[n][kk] = *(const v4i*)(pb + row * 128 + ch * 16);
            }
        }
        asm volatile("s_waitcnt lgkmcnt(0)" ::: "memory");
        __builtin_amdgcn_sched_barrier(0);
#pragma unroll
        for (int kk = 0; kk < 2; ++kk)
#pragma unroll
            for (int m = 0; m < 2; ++m)
#pragma unroll
                for (int n = 0; n < 4; ++n)
                    iacc[m][n] = __builtin_amdgcn_mfma_i32_16x16x64_i8(a[m][kk], bfr[n][kk], iacc[m][n], 0, 0, 0);
        if (t == 28) flush(0);          // seg0 ends at 29*128 = 3712
        else if (t == 30) flush(1);     // seg1 ends at 31*128 = 3968
        if (t + 2 < 32) {
            stageA((t + 2) % 3, t + 2);
            loadB(rsLoad, t + 2);
            if (t + 2 <= 28) asm volatile("s_waitcnt vmcnt(5)" ::: "memory");
            else             asm volatile("s_waitcnt vmcnt(6)" ::: "memory");
        } else {
            asm volatile("s_waitcnt vmcnt(0)" ::: "memory");
        }
        if (t + 1 < 32) {
            writeB(rsWrite, t + 1);
            asm volatile("s_waitcnt lgkmcnt(0)" ::: "memory");
        }
    };

    v4i rsA_[2], rsB_[2];
    stageA(0, 0);
    loadB(rsA_, 0);
    asm volatile("s_waitcnt vmcnt(0)" ::: "memory");
    writeB(rsA_, 0);
    stageA(1, 1);
    loadB(rsB_, 1);
    asm volatile("s_waitcnt lgkmcnt(0)" ::: "memory");

    for (int tt = 0; tt < 32; tt += 2) {
        body(tt,     rsA_, rsB_);   // loads step tt+2 -> rsA_, writes step tt+1 from rsB_
        body(tt + 1, rsB_, rsA_);
    }
    flush(2);

#pragma unroll
    for (int m = 0; m < 2; ++m)
#pragma unroll
        for (int n = 0; n < 4; ++n) {
            const int colg = col0 + n * 16 + (lane & 15);
            const float bv = bias[colg];
#pragma unroll
            for (int rr = 0; rr < 4; ++rr) {
                const int rowg = row0 + w * 32 + m * 16 + ((lane >> 4) << 2) + rr;
                out[(size_t)rowg * OF + colg] = facc[m][n][rr] + bv;
            }
        }
}

// ---------------------------------------------------------------------------
// workspace layout (bytes):
//   qX     @ 0          :  1,048,576
//   qWp    @ 1,048,576  : 24,657,920   (11008 x 2240)
//   sX     @ 25,706,496 :      3,072
//   sW     @ 25,709,568 :    132,096
//   src_of @ 25,841,664 :     16,384
//   S0X    @ 25,858,048 :      1,024
// ---------------------------------------------------------------------------
extern "C" void kernel_launch(void* const* d_in, const int* in_sizes, int n_in,
                              void* d_out, int out_size, void* d_ws, size_t ws_size,
                              hipStream_t stream) {
    const float* x    = (const float*)d_in[0];
    const float* W    = (const float*)d_in[1];
    const float* bias = (const float*)d_in[2];
    const int*   ridx = (const int*)d_in[3];
    float* out = (float*)d_out;

    uint8_t* ws = (uint8_t*)d_ws;
    int8_t*  qX  = (int8_t*)ws;
    uint8_t* qWp = ws + 1048576;
    float*   sX  = (float*)(ws + 25706496);
    float*   sW  = (float*)(ws + 25709568);
    int* src_of  = (int*)(ws + 25841664);
    int* S0X     = (int*)(ws + 25858048);

    perm_k<<<1, 256, 0, stream>>>(ridx, src_of);
    quant_k<<<T_ROWS + OF, 256, 0, stream>>>(x, W, src_of, qX, qWp, sX, sW, S0X);
    gemm_k<<<344, 256, 0, stream>>>(qX, qWp, sX, sW, S0X, bias, out);
}